// Round 10
// baseline (207.211 us; speedup 1.0000x reference)
//
#include <hip/hip_runtime.h>
#include <math.h>

// ---------------------------------------------------------------------------
// Dual CTC loss forward, linear-probability fp64 recursion, beta-normalized
// B/L split form (validated R6), forward/backward split (validated R15/R17).
// R18: allocator-friendly restructure of R17.
//  R17 post-mortem: half kernel spilled 2.7MB (115us vs predicted 60) — it
//  reverted to 16-row groups via templated lambdas recomputing addresses,
//  and carried 4 code paths incl. error float4[16]x2 buffers. Fixes:
//   - error chains: FULL-depth single blocks (R12-proven inline-f math),
//     8-row float4 groups (64 VGPR) — ~37us, off the critical path; removes
//     two code paths.
//   - phoneme halves: R9-LITERAL de-templated loops (16-row RowP4 groups,
//     precomputed nx refill pointer, interleaved refill) — the exact shape
//     that measured VGPR112 / 2KB writes / 101us at full depth.
//   - merge kernel: 32 blocks (phoneme only).
//  error task:   B=32, T=2000, C=4,  S=50   (inline f from raw logits)
//  phoneme task: B=32, T=2000, C=64, S=200  (Gph r-values, float4/lane)
// Falls back to the R2 proven path if ws too small.
// ---------------------------------------------------------------------------

static constexpr float  LOG2E = 1.4426950408889634f;
static constexpr double LN2D  = 0.6931471805599453;
static constexpr int GROWS = 2032;  // padded rows per chain

#define DPP_WAVE_SHL1   0x130
#define DPP_WAVE_SHR1   0x138
#define DPP_ROW_SHR(n)  (0x110 | (n))
#define DPP_ROW_BCAST15 0x142
#define DPP_ROW_BCAST31 0x143

__device__ __forceinline__ float fexp2(float x) {
  return __builtin_amdgcn_exp2f(x);
}
__device__ __forceinline__ float flog2(float x) {
  return __builtin_amdgcn_logf(x);
}

// prev-lane value (lane i gets lane i-1; lane 0 gets 0.0) — pure VALU
__device__ __forceinline__ double dpp_shr1_f64(double x) {
  int lo = __double2loint(x), hi = __double2hiint(x);
  lo = __builtin_amdgcn_update_dpp(0, lo, DPP_WAVE_SHR1, 0xf, 0xf, true);
  hi = __builtin_amdgcn_update_dpp(0, hi, DPP_WAVE_SHR1, 0xf, 0xf, true);
  return __hiloint2double(hi, lo);
}

// next-lane value (lane i gets lane i+1; lane 63 gets 0.0)
__device__ __forceinline__ double dpp_shl1_f64(double x) {
  int lo = __double2loint(x), hi = __double2hiint(x);
  lo = __builtin_amdgcn_update_dpp(0, lo, DPP_WAVE_SHL1, 0xf, 0xf, true);
  hi = __builtin_amdgcn_update_dpp(0, hi, DPP_WAVE_SHL1, 0xf, 0xf, true);
  return __hiloint2double(hi, lo);
}

__device__ __forceinline__ int imax2(int a, int b) { return a > b ? a : b; }

__device__ __forceinline__ int wave_imax(int v) {
  v = imax2(v, __builtin_amdgcn_update_dpp(0, v, DPP_ROW_SHR(1), 0xf, 0xf, true));
  v = imax2(v, __builtin_amdgcn_update_dpp(0, v, DPP_ROW_SHR(2), 0xf, 0xf, true));
  v = imax2(v, __builtin_amdgcn_update_dpp(0, v, DPP_ROW_SHR(4), 0xf, 0xf, true));
  v = imax2(v, __builtin_amdgcn_update_dpp(0, v, DPP_ROW_SHR(8), 0xf, 0xf, true));
  v = imax2(v, __builtin_amdgcn_update_dpp(0, v, DPP_ROW_BCAST15, 0xf, 0xf, true));
  v = imax2(v, __builtin_amdgcn_update_dpp(0, v, DPP_ROW_BCAST31, 0xf, 0xf, true));
  return __builtin_amdgcn_readlane(v, 63);
}

// wait lgkmcnt(0) only (vmcnt=63, exp=7): gfx9 encode 0xC07F = 49279
__device__ __forceinline__ void wait_lgkm0() {
  __builtin_amdgcn_sched_barrier(0);
  __builtin_amdgcn_s_waitcnt(49279);
  __builtin_amdgcn_sched_barrier(0);
}

// ========================= fast path =======================================

// Slim gather (R13-proven): phoneme r-values + both Lpb arrays + out zero.
__global__ __launch_bounds__(256) void gather_ph_kernel(
    const float* __restrict__ ph_logits, const float* __restrict__ err_logits,
    const int* __restrict__ ph_tgt,
    float* __restrict__ Gph, float* __restrict__ Lpb_ph,
    float* __restrict__ Lpb_er, float* __restrict__ out) {
  const int bx = blockIdx.x, b = blockIdx.y;
  const int tid = threadIdx.x;
  const int lane = tid & 63, wv = tid >> 6;

  if (bx == 0 && b == 0 && tid == 0) *out = 0.f;  // chain kernels come after

  // ---- error Lpb (wave 0, lanes 0..31) ----
  if (wv == 0 && lane < 32) {
    const int t = bx * 32 + lane;
    if (t < 2000) {
      const float4 v = *(const float4*)(err_logits + ((size_t)b * 2000 + t) * 4);
      const float z0 = v.x * LOG2E;
      const float s = fexp2(z0) + fexp2(v.y * LOG2E) + fexp2(v.z * LOG2E) +
                      fexp2(v.w * LOG2E);
      Lpb_er[(size_t)b * GROWS + t] = z0 - flog2(s);
    }
  }

  // ---- phoneme: 8 rows per wave ----
  const int* tb = ph_tgt + b * 200;
  int idx[4];
  float msk[4];
#pragma unroll
  for (int k = 0; k < 4; ++k) {
    const int si = lane * 4 + k;
    const int cls = (si < 200) ? tb[si] : 0;
    idx[k] = cls << 2;
    msk[k] = (si < 200) ? 1.0f : 0.0f;
  }
  const int t0 = (bx * 4 + wv) * 8;
  float z[8], e[8], s[8];
#pragma unroll
  for (int u = 0; u < 8; ++u) {
    const int t = t0 + u;
    const int tc = (t < 2000) ? t : 1999;
    z[u] = ph_logits[((size_t)b * 2000 + tc) * 64 + lane] * LOG2E;
    e[u] = fexp2(z[u]);
    s[u] = e[u];
  }
#pragma unroll
  for (int off = 32; off >= 1; off >>= 1) {
#pragma unroll
    for (int u = 0; u < 8; ++u) s[u] += __shfl_xor(s[u], off, 64);
  }
#pragma unroll
  for (int u = 0; u < 8; ++u) {
    const int t = t0 + u;
    if (t < 2000) {
      const float e0 = __int_as_float(
          __builtin_amdgcn_readlane(__float_as_int(e[u]), 0));
      const float inv0 = 1.0f / e0;
      float o[4];
#pragma unroll
      for (int k = 0; k < 4; ++k) {
        const float v = __int_as_float(
            __builtin_amdgcn_ds_bpermute(idx[k], __float_as_int(e[u])));
        o[k] = msk[k] * v * inv0;
      }
      *(float4*)(Gph + ((size_t)b * GROWS + t) * 256 + lane * 4) =
          make_float4(o[0], o[1], o[2], o[3]);
      if (lane == 0)  // lane 0's z is z0*log2e
        Lpb_ph[(size_t)b * GROWS + t] = z[u] - flog2(s[u]);
    }
  }
}

template <int P> struct RowP { float v[P]; };

__device__ __forceinline__ RowP<4> ld4(const float* p) {
  RowP<4> r;
  const float4 a = *(const float4*)p;
  r.v[0] = a.x; r.v[1] = a.y; r.v[2] = a.z; r.v[3] = a.w;
  return r;
}

// renorm band to ~2^(tgt-1023). fwd: tgt=1523 (2^500); bwd: tgt=1023 (2^0).
template <int P>
__device__ __forceinline__ void bl_renorm(double (&B)[P], double (&L)[P],
                                          int& K, int tgt) {
  double mm = B[0];
#pragma unroll
  for (int k = 0; k < P; ++k) mm = fmax(fmax(mm, B[k]), L[k]);
  const int ex = (__double2hiint(mm) >> 20) & 0x7ff;
  const int emax = wave_imax(ex);
  if (emax > 0) {
    int d = tgt - emax;
    if (d > 1023) d = 1023;
    if (d < -1022) d = -1022;
    const double sc = __hiloint2double((d + 1023) << 20, 0);
#pragma unroll
    for (int k = 0; k < P; ++k) { B[k] *= sc; L[k] *= sc; }
    K += d;
  }
}

// forward step (R9-proven): alpha over rows ascending.
template <int P>
__device__ __forceinline__ void bl_step(double (&B)[P], double (&L)[P],
                                        const double (&skipm)[P],
                                        const RowP<P>& f) {
  const double Lm1 = dpp_shr1_f64(L[P - 1]);
  double nB[P], nL[P];
#pragma unroll
  for (int k = 0; k < P; ++k) {
    const double Lp = (k >= 1) ? L[k - 1] : Lm1;
    nB[k] = B[k] + Lp;
    nL[k] = (double)f.v[k] * fma(skipm[k], Lp, B[k] + L[k]);
  }
#pragma unroll
  for (int k = 0; k < P; ++k) { B[k] = nB[k]; L[k] = nL[k]; }
}

// backward step (R15/R17-proven): beta over rows descending. f = row t+1.
template <int P>
__device__ __forceinline__ void bl_step_bwd(double (&B)[P], double (&L)[P],
                                            const double (&sknext)[P],
                                            const RowP<P>& f) {
  double w[P];
#pragma unroll
  for (int k = 0; k < P; ++k) w[k] = (double)f.v[k] * L[k];
  const double wN = dpp_shl1_f64(w[0]);   // lane i gets lane i+1's w[0]
  const double BN = dpp_shl1_f64(B[0]);   // lane i+1's B[0]
  double nB[P], nL[P];
#pragma unroll
  for (int k = 0; k < P; ++k) {
    const double wp1 = (k < P - 1) ? w[k + 1] : wN;
    const double Bp1 = (k < P - 1) ? B[k + 1] : BN;
    nB[k] = B[k] + w[k];
    nL[k] = fma(sknext[k], wp1, w[k] + Bp1);
  }
#pragma unroll
  for (int k = 0; k < P; ++k) { B[k] = nB[k]; L[k] = nL[k]; }
}

// spb = sum_{t<len} Lpb[t], lane-parallel, x8 ILP
__device__ __forceinline__ float spb_sum(const float* __restrict__ Lpb,
                                         int len, int lane) {
  float spb = 0.f;
  for (int t0 = lane; t0 < len; t0 += 512) {
#pragma unroll
    for (int u = 0; u < 8; ++u) {
      const int t = t0 + u * 64;
      const int tc = (t < len) ? t : 0;        // always-valid address
      const float v = Lpb[tc];
      spb += (t < len) ? v : 0.0f;             // cndmask, no branch
    }
  }
#pragma unroll
  for (int off = 32; off >= 1; off >>= 1) spb += __shfl_xor(spb, off, 64);
  return spb;
}

// ---------------------------------------------------------------------------
// Main kernel: 96 blocks x 64 thr.
//  blk [0,32):  error FULL chain (R12-proven inline-f math, 8-row groups),
//               writes its loss directly.
//  blk [32,64): phoneme FORWARD half  (R9-literal 16-row loop), dumps state.
//  blk [64,96): phoneme BACKWARD half (R9-shaped descending), dumps state.
// State: st + (b*4 + {0:Bf,1:Lf,2:Bb,3:Lb})*256 doubles. Ks[b]=Kf,
// Ks[32+b]=Kb. spbA[b] by ph fwd lane0.
// ---------------------------------------------------------------------------
__global__ __launch_bounds__(64) void ctc_main_kernel(
    const float* __restrict__ Gph, const float* __restrict__ err_logits,
    const int* __restrict__ ph_tgt, const int* __restrict__ err_tgt,
    const int* __restrict__ err_il, const int* __restrict__ ph_il,
    const int* __restrict__ err_tl, const int* __restrict__ ph_tl,
    const float* __restrict__ Lpb_ph, const float* __restrict__ Lpb_er,
    double* __restrict__ st, int* __restrict__ Ks, float* __restrict__ spbA,
    float* __restrict__ out) {
  __shared__ double sa[128];  // error readout only
  const int blk = blockIdx.x;
  const int lane = threadIdx.x;

  if (blk < 32) {
    // ================= error: full chain, P=1, inline f =================
    constexpr int S = 50;
    const int c = blk;
    const int* tb = err_tgt + c * 50;
    int len = err_il[c]; if (len > 2000) len = 2000;
    const int tl = err_tl[c];
    const float4* zr = (const float4*)(err_logits + (size_t)c * 2000 * 4);

    const float spb = spb_sum(Lpb_er + (size_t)c * GROWS, len, lane);
    const int c1 = tb[(lane < S) ? lane : (S - 1)];
    const float fmask = (lane < S) ? 1.0f : 0.0f;
    double skipm[1];
    skipm[0] = (lane >= 1 && lane < S && tb[lane] != tb[lane - 1]) ? 1.0 : 0.0;

    double B[1], L[1];
    B[0] = 0.0; L[0] = 0.0;
    {
      const float4 q0 = zr[0];
      const int c0 = tb[0];
      const float zc = (c0 == 1) ? q0.y : (c0 == 2) ? q0.z : q0.w;
      if (lane == 0) {
        B[0] = 1.0;
        L[0] = (double)fexp2((zc - q0.x) * LOG2E);
      }
    }
    int K = 0;

    const int nsteps = len - 1;          // rows 1..len-1
    const int ng = nsteps / 8;
    float4 bufA[8], bufB[8];
    if (ng >= 1) {
#pragma unroll
      for (int u = 0; u < 8; ++u) bufA[u] = zr[1 + u];
    }
    if (ng >= 2) {
#pragma unroll
      for (int u = 0; u < 8; ++u) bufB[u] = zr[9 + u];
    }
    int g = 0;
    for (; g + 2 <= ng; g += 2) {
      bl_renorm<1>(B, L, K, 1523);
      {
        const int gn = (g + 2 < ng) ? (g + 2) : 0;  // clamp re-reads rows 1..8
        const float4* nx = zr + 1 + gn * 8;
#pragma unroll
        for (int u = 0; u < 8; ++u) {
          RowP<1> f;
          const float4 q = bufA[u];
          const float zc = (c1 == 1) ? q.y : (c1 == 2) ? q.z : q.w;
          f.v[0] = fmask * fexp2((zc - q.x) * LOG2E);
          bl_step<1>(B, L, skipm, f);
          bufA[u] = nx[u];
        }
      }
      bl_renorm<1>(B, L, K, 1523);
      {
        const int gn = (g + 3 < ng) ? (g + 3) : 0;
        const float4* nx = zr + 1 + gn * 8;
#pragma unroll
        for (int u = 0; u < 8; ++u) {
          RowP<1> f;
          const float4 q = bufB[u];
          const float zc = (c1 == 1) ? q.y : (c1 == 2) ? q.z : q.w;
          f.v[0] = fmask * fexp2((zc - q.x) * LOG2E);
          bl_step<1>(B, L, skipm, f);
          bufB[u] = nx[u];
        }
      }
    }
    if (g < ng) {
      bl_renorm<1>(B, L, K, 1523);
#pragma unroll
      for (int u = 0; u < 8; ++u) {
        RowP<1> f;
        const float4 q = bufA[u];
        const float zc = (c1 == 1) ? q.y : (c1 == 2) ? q.z : q.w;
        f.v[0] = fmask * fexp2((zc - q.x) * LOG2E);
        bl_step<1>(B, L, skipm, f);
      }
      ++g;
    }
    {  // tail rows 1+ng*8 .. nsteps (<=7)
      const int tstart = 1 + ng * 8;
      float4 bufT[7];
#pragma unroll
      for (int u = 0; u < 7; ++u) {
        int t = tstart + u;
        if (t > nsteps) t = (nsteps > 0) ? nsteps : 1;
        bufT[u] = zr[t];
      }
#pragma unroll
      for (int u = 0; u < 7; ++u) {
        if (tstart + u <= nsteps) {
          if (u == 0) bl_renorm<1>(B, L, K, 1523);
          RowP<1> f;
          const float4 q = bufT[u];
          const float zc = (c1 == 1) ? q.y : (c1 == 2) ? q.z : q.w;
          f.v[0] = fmask * fexp2((zc - q.x) * LOG2E);
          bl_step<1>(B, L, skipm, f);
        }
      }
    }

    // readout: alpha[2tl-1] = L[tl-1], alpha[2tl] = B[tl]
    double* saB = sa;
    double* saL = sa + 64;
    saB[lane] = B[0];
    saL[lane] = L[0];
    wait_lgkm0();
    if (lane == 0) {
      const double a = saL[tl - 1] + saB[tl];
      float loss = (float)((double)K * LN2D - log(a) - (double)spb * LN2D);
      if (!(loss < 1e29f)) loss = 0.f;  // zero_infinity
      atomicAdd(out, loss / ((float)tl * 32.0f));
    }
    return;
  }

  // ================= phoneme halves, P=4 =================
  constexpr int P = 4, S = 200, LSTRIDE = 256;
  const int dir = (blk >= 64) ? 1 : 0;
  const int b = blk - (dir ? 64 : 32);
  const int* tb = ph_tgt + b * 200;
  int len = ph_il[b]; if (len > 2000) len = 2000;
  const int tl = ph_tl[b];
  const int t_mid = len >> 1;
  const float* Glab = Gph + (size_t)b * GROWS * 256;
  const float* gp = Glab + lane * P;

  double B[P], L[P];
  int K = 0;

  if (dir == 0) {
    // ---------------- forward: R9-literal 16-row loop ----------------
    const float spb = spb_sum(Lpb_ph + (size_t)b * GROWS, len, lane);
    double skipm[P];
#pragma unroll
    for (int k = 0; k < P; ++k) {
      const int s = lane * P + k;
      skipm[k] = (s >= 1 && s < S && tb[s] != tb[s - 1]) ? 1.0 : 0.0;
    }
#pragma unroll
    for (int k = 0; k < P; ++k) { B[k] = 0.0; L[k] = 0.0; }
    {
      const float r0 = Glab[0];  // lane0 slot0 = r_{tgt[0]}(0)
      if (lane == 0) { B[0] = 1.0; L[0] = (double)r0; }
    }

    const int nsteps = t_mid;            // rows 1..t_mid
    const int ngroups = nsteps / 16;
    RowP<P> bufA[16], bufB[16];
    if (ngroups >= 1) {
      const float* rb = gp + (size_t)1 * LSTRIDE;
#pragma unroll
      for (int u = 0; u < 16; ++u) bufA[u] = ld4(rb + (size_t)u * LSTRIDE);
    }
    if (ngroups >= 2) {
      const float* rb = gp + (size_t)17 * LSTRIDE;
#pragma unroll
      for (int u = 0; u < 16; ++u) bufB[u] = ld4(rb + (size_t)u * LSTRIDE);
    }
    int g = 0;
    for (; g + 2 <= ngroups; g += 2) {
      {
        bl_renorm<P>(B, L, K, 1523);
        const int gn = (g + 2 < ngroups) ? (g + 2) : 0;  // clamp: rows 1..16
        const float* nx = gp + (size_t)(1 + gn * 16) * LSTRIDE;
#pragma unroll
        for (int u = 0; u < 16; ++u) {
          bl_step<P>(B, L, skipm, bufA[u]);
          bufA[u] = ld4(nx + (size_t)u * LSTRIDE);
        }
      }
      {
        bl_renorm<P>(B, L, K, 1523);
        const int gn = (g + 3 < ngroups) ? (g + 3) : 0;
        const float* nx = gp + (size_t)(1 + gn * 16) * LSTRIDE;
#pragma unroll
        for (int u = 0; u < 16; ++u) {
          bl_step<P>(B, L, skipm, bufB[u]);
          bufB[u] = ld4(nx + (size_t)u * LSTRIDE);
        }
      }
    }
    if (g < ngroups) {  // odd ngroups: last full group sits in bufA
      bl_renorm<P>(B, L, K, 1523);
#pragma unroll
      for (int u = 0; u < 16; ++u) bl_step<P>(B, L, skipm, bufA[u]);
      ++g;
    }
    {  // tail (<=15 rows)
      const int tstart = 1 + ngroups * 16;
      RowP<P> bufT[15];
#pragma unroll
      for (int u = 0; u < 15; ++u) {
        int t = tstart + u;
        if (t > nsteps) t = (nsteps > 0) ? nsteps : 1;
        bufT[u] = ld4(gp + (size_t)t * LSTRIDE);
      }
#pragma unroll
      for (int u = 0; u < 15; ++u) {
        if (tstart + u <= nsteps) {
          if (u == 0) bl_renorm<P>(B, L, K, 1523);
          bl_step<P>(B, L, skipm, bufT[u]);
        }
      }
    }
    if (lane == 0) { Ks[b] = 0; spbA[b] = spb; }  // placeholder, fixed below
    // dump state (Bf, Lf)
    double* stB = st + ((size_t)b * 4 + 0) * 256;
    double* stL = st + ((size_t)b * 4 + 1) * 256;
#pragma unroll
    for (int k = 0; k < P; ++k) {
      stB[lane * P + k] = B[k];
      stL[lane * P + k] = L[k];
    }
    if (lane == 0) Ks[b] = K;
  } else {
    // ---------------- backward: R9-shaped descending loop ----------------
    double sknext[P];
#pragma unroll
    for (int k = 0; k < P; ++k) {
      const int s = lane * P + k;
      sknext[k] = (s + 1 < S && tb[s + 1] != tb[s]) ? 1.0 : 0.0;
    }
#pragma unroll
    for (int k = 0; k < P; ++k) {
      const int s = lane * P + k;
      B[k] = (s == tl) ? 1.0 : 0.0;       // state 2*tl (final blank)
      L[k] = (s == tl - 1) ? 1.0 : 0.0;   // state 2*tl-1 (last label)
    }

    const int M = (len - 1) - t_mid;     // rows len-1 .. t_mid+1
    const int ngroups = M / 16;
    RowP<P> bufA[16], bufB[16];
    if (ngroups >= 1) {
      const float* rb = gp + (size_t)(len - 1) * LSTRIDE;
#pragma unroll
      for (int u = 0; u < 16; ++u) bufA[u] = ld4(rb - u * LSTRIDE);
    }
    if (ngroups >= 2) {
      const float* rb = gp + (size_t)(len - 17) * LSTRIDE;
#pragma unroll
      for (int u = 0; u < 16; ++u) bufB[u] = ld4(rb - u * LSTRIDE);
    }
    int g = 0;
    for (; g + 2 <= ngroups; g += 2) {
      {
        bl_renorm<P>(B, L, K, 1023);
        const int jb = (g + 2 < ngroups) ? (g + 2) * 16 : 0;  // clamp: top rows
        const float* nx = gp + (size_t)(len - 1 - jb) * LSTRIDE;
#pragma unroll
        for (int u = 0; u < 16; ++u) {
          bl_step_bwd<P>(B, L, sknext, bufA[u]);
          bufA[u] = ld4(nx - u * LSTRIDE);
        }
      }
      {
        bl_renorm<P>(B, L, K, 1023);
        const int jb = (g + 3 < ngroups) ? (g + 3) * 16 : 0;
        const float* nx = gp + (size_t)(len - 1 - jb) * LSTRIDE;
#pragma unroll
        for (int u = 0; u < 16; ++u) {
          bl_step_bwd<P>(B, L, sknext, bufB[u]);
          bufB[u] = ld4(nx - u * LSTRIDE);
        }
      }
    }
    if (g < ngroups) {
      bl_renorm<P>(B, L, K, 1023);
#pragma unroll
      for (int u = 0; u < 16; ++u) bl_step_bwd<P>(B, L, sknext, bufA[u]);
      ++g;
    }
    {  // tail: j = ngroups*16 .. M-1, row = len-1-j (<=15)
      const int jstart = ngroups * 16;
      RowP<P> bufT[15];
#pragma unroll
      for (int u = 0; u < 15; ++u) {
        int j = jstart + u;
        if (j > M - 1) j = (M > 0) ? (M - 1) : 0;
        bufT[u] = ld4(gp + (size_t)(len - 1 - j) * LSTRIDE);
      }
#pragma unroll
      for (int u = 0; u < 15; ++u) {
        if (jstart + u < M) {
          if (u == 0) bl_renorm<P>(B, L, K, 1023);
          bl_step_bwd<P>(B, L, sknext, bufT[u]);
        }
      }
    }
    // dump state (Bb, Lb)
    double* stB = st + ((size_t)b * 4 + 2) * 256;
    double* stL = st + ((size_t)b * 4 + 3) * 256;
#pragma unroll
    for (int k = 0; k < P; ++k) {
      stB[lane * P + k] = B[k];
      stL[lane * P + k] = L[k];
    }
    if (lane == 0) Ks[32 + b] = K;
  }
}

// Merge (phoneme only): 32 blocks x 64 thr.
__global__ __launch_bounds__(64) void ctc_merge_kernel(
    const double* __restrict__ st, const int* __restrict__ Ks,
    const float* __restrict__ spbA, const int* __restrict__ ph_tl,
    float* __restrict__ out) {
  const int b = blockIdx.x;
  const int lane = threadIdx.x;
  const double* Bf = st + ((size_t)b * 4 + 0) * 256;
  const double* Lf = st + ((size_t)b * 4 + 1) * 256;
  const double* Bb = st + ((size_t)b * 4 + 2) * 256;
  const double* Lb = st + ((size_t)b * 4 + 3) * 256;
  double dot = 0.0;
#pragma unroll
  for (int k = 0; k < 4; ++k) {
    const int i = lane * 4 + k;
    dot += Bf[i] * Bb[i] + Lf[i] * Lb[i];
  }
#pragma unroll
  for (int off = 32; off >= 1; off >>= 1) dot += __shfl_xor(dot, off, 64);
  if (lane == 0) {
    const int K2 = Ks[b] + Ks[32 + b];
    const int tl = ph_tl[b];
    float loss =
        (float)((double)K2 * LN2D - log(dot) - (double)spbA[b] * LN2D);
    if (!(loss < 1e29f)) loss = 0.f;  // zero_infinity
    atomicAdd(out, loss / ((float)tl * 32.0f));
  }
}

// ========================= fallback path (R2, proven) ======================

__global__ __launch_bounds__(256) void softmax4_kernel(
    const float* __restrict__ x, float* __restrict__ p, int nrows) {
  int r = blockIdx.x * blockDim.x + threadIdx.x;
  if (r >= nrows) return;
  float4 v = *reinterpret_cast<const float4*>(x + (size_t)r * 4);
  float z0 = v.x * LOG2E, z1 = v.y * LOG2E, z2 = v.z * LOG2E, z3 = v.w * LOG2E;
  float m = fmaxf(fmaxf(z0, z1), fmaxf(z2, z3));
  float e0 = fexp2(z0 - m), e1 = fexp2(z1 - m);
  float e2 = fexp2(z2 - m), e3 = fexp2(z3 - m);
  float inv = 1.0f / (e0 + e1 + e2 + e3);
  float4 o;
  o.x = e0 * inv; o.y = e1 * inv; o.z = e2 * inv; o.w = e3 * inv;
  *reinterpret_cast<float4*>(p + (size_t)r * 4) = o;
}

__global__ __launch_bounds__(256) void softmax64_kernel(
    const float* __restrict__ x, float* __restrict__ p, int nrows) {
  int row = blockIdx.x * 4 + (threadIdx.x >> 6);
  int lane = threadIdx.x & 63;
  if (row >= nrows) return;
  float z = x[(size_t)row * 64 + lane] * LOG2E;
  float m = z;
#pragma unroll
  for (int off = 32; off >= 1; off >>= 1) m = fmaxf(m, __shfl_xor(m, off, 64));
  float e = fexp2(z - m);
  float s = e;
#pragma unroll
  for (int off = 32; off >= 1; off >>= 1) s += __shfl_xor(s, off, 64);
  p[(size_t)row * 64 + lane] = e * (1.0f / s);
}

template <int C, int S, int R>
__device__ __forceinline__ void ctc_chain_lin_fb(
    const float* __restrict__ p_b, const int* __restrict__ tgt_b,
    int len, int tl, float* __restrict__ out, double* sa) {
  constexpr int L = 2 * S + 1;
  const int lane = threadIdx.x;
  int idx[R];
  double skipm[R];
#pragma unroll
  for (int j = 0; j < R; ++j) {
    const int l = lane * R + j;
    int cls = 0;
    bool sk = false;
    if (l & 1) {
      const int s = (l - 1) >> 1;
      const int sc = (s < S) ? s : (S - 1);
      cls = tgt_b[sc];
      if (s >= 1 && s < S) sk = (cls != tgt_b[s - 1]);
    }
    idx[j] = cls * 4;
    skipm[j] = sk ? 1.0 : 0.0;
  }
  double alpha[R];
#pragma unroll
  for (int j = 0; j < R; ++j) {
    const int l = lane * R + j;
    alpha[j] = (l <= 1) ? (double)p_b[idx[j] >> 2] : 0.0;
  }
  int K = 0;
  const int cl = lane & (C - 1);
  float rv = p_b[(size_t)((1 < len - 1) ? 1 : (len - 1)) * C + cl];
  float pf[R];
#pragma unroll
  for (int j = 0; j < R; ++j)
    pf[j] = __int_as_float(__builtin_amdgcn_ds_bpermute(idx[j], __float_as_int(rv)));
  rv = p_b[(size_t)((2 < len - 1) ? 2 : (len - 1)) * C + cl];
  for (int t = 1; t < len; ++t) {
    if ((t & 31) == 0) {
      double m = alpha[0];
#pragma unroll
      for (int j = 1; j < R; ++j) m = fmax(m, alpha[j]);
#pragma unroll
      for (int off = 1; off < 64; off <<= 1) m = fmax(m, __shfl_xor(m, off, 64));
      const long long bits = __double_as_longlong(m);
      const int e = (int)((bits >> 52) & 0x7FF);
      if (e > 0) {
        const double sc = __longlong_as_double((long long)(2046 - e) << 52);
#pragma unroll
        for (int j = 0; j < R; ++j) alpha[j] *= sc;
        K += 1023 - e;
      }
    }
    const int tn = (t + 2 < len) ? (t + 2) : (len - 1);
    const float rvn = p_b[(size_t)tn * C + cl];
    float pfn[R];
#pragma unroll
    for (int j = 0; j < R; ++j)
      pfn[j] = __int_as_float(__builtin_amdgcn_ds_bpermute(idx[j], __float_as_int(rv)));
    double am1 = __shfl_up(alpha[R - 1], 1, 64);
    double am2 = __shfl_up(alpha[R - 2], 1, 64);
    if (lane == 0) { am1 = 0.0; am2 = 0.0; }
    double na[R];
#pragma unroll
    for (int j = 0; j < R; ++j) {
      const double a0 = alpha[j];
      const double a1 = (j >= 1) ? alpha[j - 1] : am1;
      const double a2 = (j >= 2) ? alpha[j - 2] : ((j == 1) ? am1 : am2);
      double s = a0 + a1;
      s = fma(skipm[j], a2, s);
      na[j] = (double)pf[j] * s;
    }
#pragma unroll
    for (int j = 0; j < R; ++j) alpha[j] = na[j];
#pragma unroll
    for (int j = 0; j < R; ++j) pf[j] = pfn[j];
    rv = rvn;
  }
#pragma unroll
  for (int j = 0; j < R; ++j) {
    const int l = lane * R + j;
    if (l < L) sa[l] = alpha[j];
  }
  __syncthreads();
  if (lane == 0) {
    const double a = sa[2 * tl - 1] + sa[2 * tl];
    float loss = (float)((double)K * LN2D - log(a));
    if (!(loss < 1e29f)) loss = 0.0f;
    atomicAdd(out, loss / ((float)tl * 32.0f));
  }
}

__global__ __launch_bounds__(64) void ctc_chains_fb_kernel(
    const float* __restrict__ p_err, const float* __restrict__ p_ph,
    const int* __restrict__ err_tgt, const int* __restrict__ ph_tgt,
    const int* __restrict__ err_il, const int* __restrict__ ph_il,
    const int* __restrict__ err_tl, const int* __restrict__ ph_tl,
    float* __restrict__ out) {
  __shared__ double sa[512];
  const int T = 2000;
  const int blk = blockIdx.x;
  if (blk < 32) {
    const int b = blk;
    int len = err_il[b]; if (len > T) len = T;
    ctc_chain_lin_fb<4, 50, 2>(p_err + (size_t)b * T * 4, err_tgt + b * 50, len,
                               err_tl[b], out, sa);
  } else {
    const int b = blk - 32;
    int len = ph_il[b]; if (len > T) len = T;
    ctc_chain_lin_fb<64, 200, 7>(p_ph + (size_t)b * T * 64, ph_tgt + b * 200,
                                 len, ph_tl[b], out, sa);
  }
}

// ========================= launch ==========================================

extern "C" void kernel_launch(void* const* d_in, const int* in_sizes, int n_in,
                              void* d_out, int out_size, void* d_ws,
                              size_t ws_size, hipStream_t stream) {
  const float* err_logits = (const float*)d_in[0];
  const float* ph_logits  = (const float*)d_in[1];
  const int* err_tgt = (const int*)d_in[2];
  const int* ph_tgt  = (const int*)d_in[3];
  const int* err_il  = (const int*)d_in[4];
  const int* ph_il   = (const int*)d_in[5];
  const int* err_tl  = (const int*)d_in[6];
  const int* ph_tl   = (const int*)d_in[7];
  float* out = (float*)d_out;

  const size_t gph = (size_t)32 * GROWS * 256;  // floats, 66.6 MB
  const size_t lpb = (size_t)32 * GROWS;        // floats, per task
  const size_t nst = (size_t)32 * 4 * 256;      // doubles, 256 KB
  const size_t need =
      (gph + 2 * lpb) * sizeof(float) + nst * sizeof(double) + 128 * 4;

  if (ws_size >= need) {
    float* Gph = (float*)d_ws;
    float* Lpb_ph = Gph + gph;
    float* Lpb_er = Lpb_ph + lpb;
    double* st = (double*)(Lpb_er + lpb);  // 8B-aligned (offsets 8B multiple)
    int* Ks = (int*)(st + nst);            // 64 ints
    float* spbA = (float*)(Ks + 64);       // 32 floats
    // gather zeroes *out (chain kernels are stream-ordered after it)
    gather_ph_kernel<<<dim3(63, 32), 256, 0, stream>>>(
        ph_logits, err_logits, ph_tgt, Gph, Lpb_ph, Lpb_er, out);
    ctc_main_kernel<<<96, 64, 0, stream>>>(
        Gph, err_logits, ph_tgt, err_tgt, err_il, ph_il, err_tl, ph_tl,
        Lpb_ph, Lpb_er, st, Ks, spbA, out);
    ctc_merge_kernel<<<32, 64, 0, stream>>>(st, Ks, spbA, ph_tl, out);
  } else {
    (void)hipMemsetAsync(d_out, 0, sizeof(float), stream);
    const int B = 32, T = 2000;
    const int rows = B * T;
    float* p_err = (float*)d_ws;
    float* p_ph  = p_err + (size_t)rows * 4;
    softmax4_kernel<<<(rows + 255) / 256, 256, 0, stream>>>(err_logits, p_err, rows);
    softmax64_kernel<<<(rows + 3) / 4, 256, 0, stream>>>(ph_logits, p_ph, rows);
    ctc_chains_fb_kernel<<<64, 64, 0, stream>>>(p_err, p_ph, err_tgt, ph_tgt,
                                                err_il, ph_il, err_tl, ph_tl, out);
  }
}

// Round 11
// 201.866 us; speedup vs baseline: 1.0265x; 1.0265x over previous
//
#include <hip/hip_runtime.h>
#include <math.h>

// ---------------------------------------------------------------------------
// Dual CTC loss forward, linear-probability fp64 recursion, beta-normalized
// B/L split form (validated R6), R9-proven interleaved register prefetch.
// R19: best-of-proven-pieces assembly.
//  R15-R18 post-mortem: every fwd/bwd-split variant lands at 115-125us chain
//  regardless of spill (R18 removed spill entirely: WRITE 3.1MB->260KB,
//  dur 121->125). Halving serial depth bought nothing in 4 tries; the bwd
//  path runs ~290 cyc/step (serial dep-chain routes the per-step DPP through
//  this step's load->cvt->mul). Dropped.
//  Meanwhile R9's chain (101us, full-depth fwd, VGPR112/2KB-writes) was
//  never paired with the R13 slim gather (33us, no memsets) — R13 changed
//  the chain simultaneously. This round: exactly that pairing, 2 dispatches.
//   - gather: R13/R18-proven slim gather (Gph + Lpb_ph + Lpb_er + out=0).
//   - chain: blocks 0-31 error full-depth inline-f (R18-proven, ~40us,
//     hidden); blocks 32-63 phoneme full-depth R9-literal forward.
//  error task:   B=32, T=2000, C=4,  S=50   (inline f from raw logits)
//  phoneme task: B=32, T=2000, C=64, S=200  (Gph r-values, float4/lane)
// Falls back to the R2 proven path if ws too small.
// ---------------------------------------------------------------------------

static constexpr float  LOG2E = 1.4426950408889634f;
static constexpr double LN2D  = 0.6931471805599453;
static constexpr int GROWS = 2032;  // padded rows per chain

#define DPP_WAVE_SHR1   0x138
#define DPP_ROW_SHR(n)  (0x110 | (n))
#define DPP_ROW_BCAST15 0x142
#define DPP_ROW_BCAST31 0x143

__device__ __forceinline__ float fexp2(float x) {
  return __builtin_amdgcn_exp2f(x);
}
__device__ __forceinline__ float flog2(float x) {
  return __builtin_amdgcn_logf(x);
}

// prev-lane value (lane i gets lane i-1; lane 0 gets 0.0) — pure VALU
__device__ __forceinline__ double dpp_shr1_f64(double x) {
  int lo = __double2loint(x), hi = __double2hiint(x);
  lo = __builtin_amdgcn_update_dpp(0, lo, DPP_WAVE_SHR1, 0xf, 0xf, true);
  hi = __builtin_amdgcn_update_dpp(0, hi, DPP_WAVE_SHR1, 0xf, 0xf, true);
  return __hiloint2double(hi, lo);
}

__device__ __forceinline__ int imax2(int a, int b) { return a > b ? a : b; }

__device__ __forceinline__ int wave_imax(int v) {
  v = imax2(v, __builtin_amdgcn_update_dpp(0, v, DPP_ROW_SHR(1), 0xf, 0xf, true));
  v = imax2(v, __builtin_amdgcn_update_dpp(0, v, DPP_ROW_SHR(2), 0xf, 0xf, true));
  v = imax2(v, __builtin_amdgcn_update_dpp(0, v, DPP_ROW_SHR(4), 0xf, 0xf, true));
  v = imax2(v, __builtin_amdgcn_update_dpp(0, v, DPP_ROW_SHR(8), 0xf, 0xf, true));
  v = imax2(v, __builtin_amdgcn_update_dpp(0, v, DPP_ROW_BCAST15, 0xf, 0xf, true));
  v = imax2(v, __builtin_amdgcn_update_dpp(0, v, DPP_ROW_BCAST31, 0xf, 0xf, true));
  return __builtin_amdgcn_readlane(v, 63);
}

// wait lgkmcnt(0) only (vmcnt=63, exp=7): gfx9 encode 0xC07F = 49279
__device__ __forceinline__ void wait_lgkm0() {
  __builtin_amdgcn_sched_barrier(0);
  __builtin_amdgcn_s_waitcnt(49279);
  __builtin_amdgcn_sched_barrier(0);
}

// ========================= fast path =======================================

// Slim gather (R13/R18-proven): phoneme r-values + both Lpb arrays + out=0.
__global__ __launch_bounds__(256) void gather_ph_kernel(
    const float* __restrict__ ph_logits, const float* __restrict__ err_logits,
    const int* __restrict__ ph_tgt,
    float* __restrict__ Gph, float* __restrict__ Lpb_ph,
    float* __restrict__ Lpb_er, float* __restrict__ out) {
  const int bx = blockIdx.x, b = blockIdx.y;
  const int tid = threadIdx.x;
  const int lane = tid & 63, wv = tid >> 6;

  if (bx == 0 && b == 0 && tid == 0) *out = 0.f;  // chain kernel comes after

  // ---- error Lpb (wave 0, lanes 0..31) ----
  if (wv == 0 && lane < 32) {
    const int t = bx * 32 + lane;
    if (t < 2000) {
      const float4 v = *(const float4*)(err_logits + ((size_t)b * 2000 + t) * 4);
      const float z0 = v.x * LOG2E;
      const float s = fexp2(z0) + fexp2(v.y * LOG2E) + fexp2(v.z * LOG2E) +
                      fexp2(v.w * LOG2E);
      Lpb_er[(size_t)b * GROWS + t] = z0 - flog2(s);
    }
  }

  // ---- phoneme: 8 rows per wave ----
  const int* tb = ph_tgt + b * 200;
  int idx[4];
  float msk[4];
#pragma unroll
  for (int k = 0; k < 4; ++k) {
    const int si = lane * 4 + k;
    const int cls = (si < 200) ? tb[si] : 0;
    idx[k] = cls << 2;
    msk[k] = (si < 200) ? 1.0f : 0.0f;
  }
  const int t0 = (bx * 4 + wv) * 8;
  float z[8], e[8], s[8];
#pragma unroll
  for (int u = 0; u < 8; ++u) {
    const int t = t0 + u;
    const int tc = (t < 2000) ? t : 1999;
    z[u] = ph_logits[((size_t)b * 2000 + tc) * 64 + lane] * LOG2E;
    e[u] = fexp2(z[u]);
    s[u] = e[u];
  }
#pragma unroll
  for (int off = 32; off >= 1; off >>= 1) {
#pragma unroll
    for (int u = 0; u < 8; ++u) s[u] += __shfl_xor(s[u], off, 64);
  }
#pragma unroll
  for (int u = 0; u < 8; ++u) {
    const int t = t0 + u;
    if (t < 2000) {
      const float e0 = __int_as_float(
          __builtin_amdgcn_readlane(__float_as_int(e[u]), 0));
      const float inv0 = 1.0f / e0;
      float o[4];
#pragma unroll
      for (int k = 0; k < 4; ++k) {
        const float v = __int_as_float(
            __builtin_amdgcn_ds_bpermute(idx[k], __float_as_int(e[u])));
        o[k] = msk[k] * v * inv0;
      }
      *(float4*)(Gph + ((size_t)b * GROWS + t) * 256 + lane * 4) =
          make_float4(o[0], o[1], o[2], o[3]);
      if (lane == 0)  // lane 0's z is z0*log2e
        Lpb_ph[(size_t)b * GROWS + t] = z[u] - flog2(s[u]);
    }
  }
}

template <int P> struct RowP { float v[P]; };

__device__ __forceinline__ RowP<4> ld4(const float* p) {
  RowP<4> r;
  const float4 a = *(const float4*)p;
  r.v[0] = a.x; r.v[1] = a.y; r.v[2] = a.z; r.v[3] = a.w;
  return r;
}

// renorm band to ~2^500 (fwd-proven band pin).
template <int P>
__device__ __forceinline__ void bl_renorm(double (&B)[P], double (&L)[P],
                                          int& K) {
  double mm = B[0];
#pragma unroll
  for (int k = 0; k < P; ++k) mm = fmax(fmax(mm, B[k]), L[k]);
  const int ex = (__double2hiint(mm) >> 20) & 0x7ff;
  const int emax = wave_imax(ex);
  if (emax > 0) {
    int d = 1523 - emax;            // pin band max to ~2^500
    if (d > 1023) d = 1023;
    if (d < -1022) d = -1022;
    const double sc = __hiloint2double((d + 1023) << 20, 0);
#pragma unroll
    for (int k = 0; k < P; ++k) { B[k] *= sc; L[k] *= sc; }
    K += d;
  }
}

// forward step (R9-proven): alpha over rows ascending.
template <int P>
__device__ __forceinline__ void bl_step(double (&B)[P], double (&L)[P],
                                        const double (&skipm)[P],
                                        const RowP<P>& f) {
  const double Lm1 = dpp_shr1_f64(L[P - 1]);
  double nB[P], nL[P];
#pragma unroll
  for (int k = 0; k < P; ++k) {
    const double Lp = (k >= 1) ? L[k - 1] : Lm1;
    nB[k] = B[k] + Lp;
    nL[k] = (double)f.v[k] * fma(skipm[k], Lp, B[k] + L[k]);
  }
#pragma unroll
  for (int k = 0; k < P; ++k) { B[k] = nB[k]; L[k] = nL[k]; }
}

// spb = sum_{t<len} Lpb[t], lane-parallel, x8 ILP
__device__ __forceinline__ float spb_sum(const float* __restrict__ Lpb,
                                         int len, int lane) {
  float spb = 0.f;
  for (int t0 = lane; t0 < len; t0 += 512) {
#pragma unroll
    for (int u = 0; u < 8; ++u) {
      const int t = t0 + u * 64;
      const int tc = (t < len) ? t : 0;        // always-valid address
      const float v = Lpb[tc];
      spb += (t < len) ? v : 0.0f;             // cndmask, no branch
    }
  }
#pragma unroll
  for (int off = 32; off >= 1; off >>= 1) spb += __shfl_xor(spb, off, 64);
  return spb;
}

// ---------------------------------------------------------------------------
// Chain kernel: 64 blocks x 64 thr.
//  blk [0,32):  error FULL chain (R18-proven inline-f, 8-row float4 groups).
//  blk [32,64): phoneme FULL chain (R9-literal 16-row interleaved refill).
// ---------------------------------------------------------------------------
__global__ __launch_bounds__(64) void ctc_chains2_kernel(
    const float* __restrict__ Gph, const float* __restrict__ err_logits,
    const int* __restrict__ ph_tgt, const int* __restrict__ err_tgt,
    const int* __restrict__ err_il, const int* __restrict__ ph_il,
    const int* __restrict__ err_tl, const int* __restrict__ ph_tl,
    const float* __restrict__ Lpb_ph, const float* __restrict__ Lpb_er,
    float* __restrict__ out) {
  __shared__ double sa[512];
  const int blk = blockIdx.x;
  const int lane = threadIdx.x;

  if (blk < 32) {
    // ================= error: full chain, P=1, inline f =================
    constexpr int S = 50;
    const int c = blk;
    const int* tb = err_tgt + c * 50;
    int len = err_il[c]; if (len > 2000) len = 2000;
    const int tl = err_tl[c];
    const float4* zr = (const float4*)(err_logits + (size_t)c * 2000 * 4);

    const float spb = spb_sum(Lpb_er + (size_t)c * GROWS, len, lane);
    const int c1 = tb[(lane < S) ? lane : (S - 1)];
    const float fmask = (lane < S) ? 1.0f : 0.0f;
    double skipm[1];
    skipm[0] = (lane >= 1 && lane < S && tb[lane] != tb[lane - 1]) ? 1.0 : 0.0;

    double B[1], L[1];
    B[0] = 0.0; L[0] = 0.0;
    {
      const float4 q0 = zr[0];
      const int c0 = tb[0];
      const float zc = (c0 == 1) ? q0.y : (c0 == 2) ? q0.z : q0.w;
      if (lane == 0) {
        B[0] = 1.0;
        L[0] = (double)fexp2((zc - q0.x) * LOG2E);
      }
    }
    int K = 0;

    const int nsteps = len - 1;          // rows 1..len-1
    const int ng = nsteps / 8;
    float4 bufA[8], bufB[8];
    if (ng >= 1) {
#pragma unroll
      for (int u = 0; u < 8; ++u) bufA[u] = zr[1 + u];
    }
    if (ng >= 2) {
#pragma unroll
      for (int u = 0; u < 8; ++u) bufB[u] = zr[9 + u];
    }
    int g = 0;
    for (; g + 2 <= ng; g += 2) {
      bl_renorm<1>(B, L, K);
      {
        const int gn = (g + 2 < ng) ? (g + 2) : 0;  // clamp re-reads rows 1..8
        const float4* nx = zr + 1 + gn * 8;
#pragma unroll
        for (int u = 0; u < 8; ++u) {
          RowP<1> f;
          const float4 q = bufA[u];
          const float zc = (c1 == 1) ? q.y : (c1 == 2) ? q.z : q.w;
          f.v[0] = fmask * fexp2((zc - q.x) * LOG2E);
          bl_step<1>(B, L, skipm, f);
          bufA[u] = nx[u];
        }
      }
      bl_renorm<1>(B, L, K);
      {
        const int gn = (g + 3 < ng) ? (g + 3) : 0;
        const float4* nx = zr + 1 + gn * 8;
#pragma unroll
        for (int u = 0; u < 8; ++u) {
          RowP<1> f;
          const float4 q = bufB[u];
          const float zc = (c1 == 1) ? q.y : (c1 == 2) ? q.z : q.w;
          f.v[0] = fmask * fexp2((zc - q.x) * LOG2E);
          bl_step<1>(B, L, skipm, f);
          bufB[u] = nx[u];
        }
      }
    }
    if (g < ng) {
      bl_renorm<1>(B, L, K);
#pragma unroll
      for (int u = 0; u < 8; ++u) {
        RowP<1> f;
        const float4 q = bufA[u];
        const float zc = (c1 == 1) ? q.y : (c1 == 2) ? q.z : q.w;
        f.v[0] = fmask * fexp2((zc - q.x) * LOG2E);
        bl_step<1>(B, L, skipm, f);
      }
      ++g;
    }
    {  // tail rows 1+ng*8 .. nsteps (<=7)
      const int tstart = 1 + ng * 8;
      float4 bufT[7];
#pragma unroll
      for (int u = 0; u < 7; ++u) {
        int t = tstart + u;
        if (t > nsteps) t = (nsteps > 0) ? nsteps : 1;
        bufT[u] = zr[t];
      }
#pragma unroll
      for (int u = 0; u < 7; ++u) {
        if (tstart + u <= nsteps) {
          if (u == 0) bl_renorm<1>(B, L, K);
          RowP<1> f;
          const float4 q = bufT[u];
          const float zc = (c1 == 1) ? q.y : (c1 == 2) ? q.z : q.w;
          f.v[0] = fmask * fexp2((zc - q.x) * LOG2E);
          bl_step<1>(B, L, skipm, f);
        }
      }
    }

    // readout: alpha[2tl-1] = L[tl-1], alpha[2tl] = B[tl]
    double* saB = sa;
    double* saL = sa + 64;
    saB[lane] = B[0];
    saL[lane] = L[0];
    wait_lgkm0();
    if (lane == 0) {
      const double a = saL[tl - 1] + saB[tl];
      float loss = (float)((double)K * LN2D - log(a) - (double)spb * LN2D);
      if (!(loss < 1e29f)) loss = 0.f;  // zero_infinity
      atomicAdd(out, loss / ((float)tl * 32.0f));
    }
    return;
  }

  // ================= phoneme: full chain, P=4, R9-literal =================
  constexpr int P = 4, S = 200, LSTRIDE = 256;
  const int b = blk - 32;
  const int* tb = ph_tgt + b * 200;
  int len = ph_il[b]; if (len > 2000) len = 2000;
  const int tl = ph_tl[b];
  const float* Glab = Gph + (size_t)b * GROWS * 256;
  const float* gp = Glab + lane * P;

  const float spb = spb_sum(Lpb_ph + (size_t)b * GROWS, len, lane);

  double skipm[P];
#pragma unroll
  for (int k = 0; k < P; ++k) {
    const int s = lane * P + k;
    skipm[k] = (s >= 1 && s < S && tb[s] != tb[s - 1]) ? 1.0 : 0.0;
  }

  double B[P], L[P];
#pragma unroll
  for (int k = 0; k < P; ++k) { B[k] = 0.0; L[k] = 0.0; }
  {
    const float r0 = Glab[0];  // lane0 slot0 = r_{tgt[0]}(0)
    if (lane == 0) { B[0] = 1.0; L[0] = (double)r0; }
  }
  int K = 0;

  const int ngroups = (len - 1) / 16;    // full groups: rows 1+16g..16+16g

  RowP<P> bufA[16], bufB[16];
  if (ngroups >= 1) {
    const float* rb = gp + (size_t)1 * LSTRIDE;
#pragma unroll
    for (int u = 0; u < 16; ++u) bufA[u] = ld4(rb + (size_t)u * LSTRIDE);
  }
  if (ngroups >= 2) {
    const float* rb = gp + (size_t)17 * LSTRIDE;
#pragma unroll
    for (int u = 0; u < 16; ++u) bufB[u] = ld4(rb + (size_t)u * LSTRIDE);
  }

  int g = 0;
  for (; g + 2 <= ngroups; g += 2) {
    // ---- group g from bufA; per-step refill with group g+2 (clamped) ----
    {
      bl_renorm<P>(B, L, K);
      const int gn = (g + 2 < ngroups) ? (g + 2) : 0;  // clamp: rows 1..16
      const float* nx = gp + (size_t)(1 + gn * 16) * LSTRIDE;
#pragma unroll
      for (int u = 0; u < 16; ++u) {
        bl_step<P>(B, L, skipm, bufA[u]);
        bufA[u] = ld4(nx + (size_t)u * LSTRIDE);
      }
    }
    // ---- group g+1 from bufB; per-step refill with group g+3 ----
    {
      bl_renorm<P>(B, L, K);
      const int gn = (g + 3 < ngroups) ? (g + 3) : 0;
      const float* nx = gp + (size_t)(1 + gn * 16) * LSTRIDE;
#pragma unroll
      for (int u = 0; u < 16; ++u) {
        bl_step<P>(B, L, skipm, bufB[u]);
        bufB[u] = ld4(nx + (size_t)u * LSTRIDE);
      }
    }
  }
  if (g < ngroups) {  // odd ngroups: last full group sits in bufA
    bl_renorm<P>(B, L, K);
#pragma unroll
    for (int u = 0; u < 16; ++u) bl_step<P>(B, L, skipm, bufA[u]);
    ++g;
  }

  // tail (<=15 rows): batch-prefetch, one latency hit total.
  {
    const int tstart = 1 + ngroups * 16;
    RowP<P> bufT[15];
#pragma unroll
    for (int u = 0; u < 15; ++u) {
      int t = tstart + u;
      if (t > len - 1) t = len - 1;            // always-valid address
      bufT[u] = ld4(gp + (size_t)t * LSTRIDE);
    }
#pragma unroll
    for (int u = 0; u < 15; ++u) {
      const int t = tstart + u;
      if (t < len) {
        if (u == 0) bl_renorm<P>(B, L, K);     // (t-1) = 16*ngroups == 0 mod 16
        bl_step<P>(B, L, skipm, bufT[u]);
      }
    }
  }

  // readout: alpha[2tl-1] = L[tl-1], alpha[2tl] = B[tl]
  double* saB = sa;
  double* saL = sa + 64 * P;
#pragma unroll
  for (int k = 0; k < P; ++k) {
    saB[lane * P + k] = B[k];
    saL[lane * P + k] = L[k];
  }
  wait_lgkm0();  // single-wave block: drain ds_writes, no barrier needed
  if (lane == 0) {
    const double a = saL[tl - 1] + saB[tl];
    float loss = (float)((double)K * LN2D - log(a) - (double)spb * LN2D);
    if (!(loss < 1e29f)) loss = 0.f;  // zero_infinity
    atomicAdd(out, loss / ((float)tl * 32.0f));
  }
}

// ========================= fallback path (R2, proven) ======================

__global__ __launch_bounds__(256) void softmax4_kernel(
    const float* __restrict__ x, float* __restrict__ p, int nrows) {
  int r = blockIdx.x * blockDim.x + threadIdx.x;
  if (r >= nrows) return;
  float4 v = *reinterpret_cast<const float4*>(x + (size_t)r * 4);
  float z0 = v.x * LOG2E, z1 = v.y * LOG2E, z2 = v.z * LOG2E, z3 = v.w * LOG2E;
  float m = fmaxf(fmaxf(z0, z1), fmaxf(z2, z3));
  float e0 = fexp2(z0 - m), e1 = fexp2(z1 - m);
  float e2 = fexp2(z2 - m), e3 = fexp2(z3 - m);
  float inv = 1.0f / (e0 + e1 + e2 + e3);
  float4 o;
  o.x = e0 * inv; o.y = e1 * inv; o.z = e2 * inv; o.w = e3 * inv;
  *reinterpret_cast<float4*>(p + (size_t)r * 4) = o;
}

__global__ __launch_bounds__(256) void softmax64_kernel(
    const float* __restrict__ x, float* __restrict__ p, int nrows) {
  int row = blockIdx.x * 4 + (threadIdx.x >> 6);
  int lane = threadIdx.x & 63;
  if (row >= nrows) return;
  float z = x[(size_t)row * 64 + lane] * LOG2E;
  float m = z;
#pragma unroll
  for (int off = 32; off >= 1; off >>= 1) m = fmaxf(m, __shfl_xor(m, off, 64));
  float e = fexp2(z - m);
  float s = e;
#pragma unroll
  for (int off = 32; off >= 1; off >>= 1) s += __shfl_xor(s, off, 64);
  p[(size_t)row * 64 + lane] = e * (1.0f / s);
}

template <int C, int S, int R>
__device__ __forceinline__ void ctc_chain_lin_fb(
    const float* __restrict__ p_b, const int* __restrict__ tgt_b,
    int len, int tl, float* __restrict__ out, double* sa) {
  constexpr int L = 2 * S + 1;
  const int lane = threadIdx.x;
  int idx[R];
  double skipm[R];
#pragma unroll
  for (int j = 0; j < R; ++j) {
    const int l = lane * R + j;
    int cls = 0;
    bool sk = false;
    if (l & 1) {
      const int s = (l - 1) >> 1;
      const int sc = (s < S) ? s : (S - 1);
      cls = tgt_b[sc];
      if (s >= 1 && s < S) sk = (cls != tgt_b[s - 1]);
    }
    idx[j] = cls * 4;
    skipm[j] = sk ? 1.0 : 0.0;
  }
  double alpha[R];
#pragma unroll
  for (int j = 0; j < R; ++j) {
    const int l = lane * R + j;
    alpha[j] = (l <= 1) ? (double)p_b[idx[j] >> 2] : 0.0;
  }
  int K = 0;
  const int cl = lane & (C - 1);
  float rv = p_b[(size_t)((1 < len - 1) ? 1 : (len - 1)) * C + cl];
  float pf[R];
#pragma unroll
  for (int j = 0; j < R; ++j)
    pf[j] = __int_as_float(__builtin_amdgcn_ds_bpermute(idx[j], __float_as_int(rv)));
  rv = p_b[(size_t)((2 < len - 1) ? 2 : (len - 1)) * C + cl];
  for (int t = 1; t < len; ++t) {
    if ((t & 31) == 0) {
      double m = alpha[0];
#pragma unroll
      for (int j = 1; j < R; ++j) m = fmax(m, alpha[j]);
#pragma unroll
      for (int off = 1; off < 64; off <<= 1) m = fmax(m, __shfl_xor(m, off, 64));
      const long long bits = __double_as_longlong(m);
      const int e = (int)((bits >> 52) & 0x7FF);
      if (e > 0) {
        const double sc = __longlong_as_double((long long)(2046 - e) << 52);
#pragma unroll
        for (int j = 0; j < R; ++j) alpha[j] *= sc;
        K += 1023 - e;
      }
    }
    const int tn = (t + 2 < len) ? (t + 2) : (len - 1);
    const float rvn = p_b[(size_t)tn * C + cl];
    float pfn[R];
#pragma unroll
    for (int j = 0; j < R; ++j)
      pfn[j] = __int_as_float(__builtin_amdgcn_ds_bpermute(idx[j], __float_as_int(rv)));
    double am1 = __shfl_up(alpha[R - 1], 1, 64);
    double am2 = __shfl_up(alpha[R - 2], 1, 64);
    if (lane == 0) { am1 = 0.0; am2 = 0.0; }
    double na[R];
#pragma unroll
    for (int j = 0; j < R; ++j) {
      const double a0 = alpha[j];
      const double a1 = (j >= 1) ? alpha[j - 1] : am1;
      const double a2 = (j >= 2) ? alpha[j - 2] : ((j == 1) ? am1 : am2);
      double s = a0 + a1;
      s = fma(skipm[j], a2, s);
      na[j] = (double)pf[j] * s;
    }
#pragma unroll
    for (int j = 0; j < R; ++j) alpha[j] = na[j];
#pragma unroll
    for (int j = 0; j < R; ++j) pf[j] = pfn[j];
    rv = rvn;
  }
#pragma unroll
  for (int j = 0; j < R; ++j) {
    const int l = lane * R + j;
    if (l < L) sa[l] = alpha[j];
  }
  __syncthreads();
  if (lane == 0) {
    const double a = sa[2 * tl - 1] + sa[2 * tl];
    float loss = (float)((double)K * LN2D - log(a));
    if (!(loss < 1e29f)) loss = 0.0f;
    atomicAdd(out, loss / ((float)tl * 32.0f));
  }
}

__global__ __launch_bounds__(64) void ctc_chains_fb_kernel(
    const float* __restrict__ p_err, const float* __restrict__ p_ph,
    const int* __restrict__ err_tgt, const int* __restrict__ ph_tgt,
    const int* __restrict__ err_il, const int* __restrict__ ph_il,
    const int* __restrict__ err_tl, const int* __restrict__ ph_tl,
    float* __restrict__ out) {
  __shared__ double sa[512];
  const int T = 2000;
  const int blk = blockIdx.x;
  if (blk < 32) {
    const int b = blk;
    int len = err_il[b]; if (len > T) len = T;
    ctc_chain_lin_fb<4, 50, 2>(p_err + (size_t)b * T * 4, err_tgt + b * 50, len,
                               err_tl[b], out, sa);
  } else {
    const int b = blk - 32;
    int len = ph_il[b]; if (len > T) len = T;
    ctc_chain_lin_fb<64, 200, 7>(p_ph + (size_t)b * T * 64, ph_tgt + b * 200,
                                 len, ph_tl[b], out, sa);
  }
}

// ========================= launch ==========================================

extern "C" void kernel_launch(void* const* d_in, const int* in_sizes, int n_in,
                              void* d_out, int out_size, void* d_ws,
                              size_t ws_size, hipStream_t stream) {
  const float* err_logits = (const float*)d_in[0];
  const float* ph_logits  = (const float*)d_in[1];
  const int* err_tgt = (const int*)d_in[2];
  const int* ph_tgt  = (const int*)d_in[3];
  const int* err_il  = (const int*)d_in[4];
  const int* ph_il   = (const int*)d_in[5];
  const int* err_tl  = (const int*)d_in[6];
  const int* ph_tl   = (const int*)d_in[7];
  float* out = (float*)d_out;

  const size_t gph = (size_t)32 * GROWS * 256;  // floats, 66.6 MB
  const size_t lpb = (size_t)32 * GROWS;        // floats, per task
  const size_t need = (gph + 2 * lpb) * sizeof(float);

  if (ws_size >= need) {
    float* Gph = (float*)d_ws;
    float* Lpb_ph = Gph + gph;
    float* Lpb_er = Lpb_ph + lpb;
    // gather zeroes *out (chain kernel is stream-ordered after it)
    gather_ph_kernel<<<dim3(63, 32), 256, 0, stream>>>(
        ph_logits, err_logits, ph_tgt, Gph, Lpb_ph, Lpb_er, out);
    ctc_chains2_kernel<<<64, 64, 0, stream>>>(
        Gph, err_logits, ph_tgt, err_tgt, err_il, ph_il, err_tl, ph_tl,
        Lpb_ph, Lpb_er, out);
  } else {
    (void)hipMemsetAsync(d_out, 0, sizeof(float), stream);
    const int B = 32, T = 2000;
    const int rows = B * T;
    float* p_err = (float*)d_ws;
    float* p_ph  = p_err + (size_t)rows * 4;
    softmax4_kernel<<<(rows + 255) / 256, 256, 0, stream>>>(err_logits, p_err, rows);
    softmax64_kernel<<<(rows + 3) / 4, 256, 0, stream>>>(ph_logits, p_ph, rows);
    ctc_chains_fb_kernel<<<64, 64, 0, stream>>>(p_err, p_ph, err_tgt, ph_tgt,
                                                err_il, ph_il, err_tl, ph_tl, out);
  }
}

// Round 12
// 201.550 us; speedup vs baseline: 1.0281x; 1.0016x over previous
//
#include <hip/hip_runtime.h>
#include <math.h>

// ---------------------------------------------------------------------------
// Dual CTC loss forward, linear-probability fp64 recursion, beta-normalized
// B/L split form (validated R6), R9-proven interleaved register prefetch.
// R20: packed-FP64 phoneme step.
//  R19 landed chain=118.5us (vs R9's 101) — codegen delta unexplained by
//  counters. Rather than chase it, exploit the one unused mechanism on the
//  dominant cost: the phoneme step is pure f64 VALU issue (~20 scalar ops =
//  ~80cyc at 4cyc/wave64-op). CDNA (gfx90a+) has packed FP64
//  (v_pk_add/mul/fma_f64): one inst = 2 f64/lane. The backend selects it
//  for LLVM <2 x double>, which clang ext_vector_type(2) produces. So the
//  B/L state becomes double2 pairs (B01,B23,L01,L23): 8 packed ops + 4 cvt
//  per step, modeled issue 80 -> ~45-50 cyc/step.
//  Neighbor terms Lp01=(Lm1,L01.x), Lp23=(L01.y,L23.x) are shufflevectors.
//  Numerically identical elementwise. Everything else = R19 verbatim.
//  error task:   B=32, T=2000, C=4,  S=50   (inline f from raw logits)
//  phoneme task: B=32, T=2000, C=64, S=200  (Gph r-values, float4/lane)
// Falls back to the R2 proven path if ws too small.
// ---------------------------------------------------------------------------

static constexpr float  LOG2E = 1.4426950408889634f;
static constexpr double LN2D  = 0.6931471805599453;
static constexpr int GROWS = 2032;  // padded rows per chain

typedef double v2d __attribute__((ext_vector_type(2)));

#define DPP_WAVE_SHR1   0x138
#define DPP_ROW_SHR(n)  (0x110 | (n))
#define DPP_ROW_BCAST15 0x142
#define DPP_ROW_BCAST31 0x143

__device__ __forceinline__ float fexp2(float x) {
  return __builtin_amdgcn_exp2f(x);
}
__device__ __forceinline__ float flog2(float x) {
  return __builtin_amdgcn_logf(x);
}

// prev-lane value (lane i gets lane i-1; lane 0 gets 0.0) — pure VALU
__device__ __forceinline__ double dpp_shr1_f64(double x) {
  int lo = __double2loint(x), hi = __double2hiint(x);
  lo = __builtin_amdgcn_update_dpp(0, lo, DPP_WAVE_SHR1, 0xf, 0xf, true);
  hi = __builtin_amdgcn_update_dpp(0, hi, DPP_WAVE_SHR1, 0xf, 0xf, true);
  return __hiloint2double(hi, lo);
}

__device__ __forceinline__ int imax2(int a, int b) { return a > b ? a : b; }

__device__ __forceinline__ int wave_imax(int v) {
  v = imax2(v, __builtin_amdgcn_update_dpp(0, v, DPP_ROW_SHR(1), 0xf, 0xf, true));
  v = imax2(v, __builtin_amdgcn_update_dpp(0, v, DPP_ROW_SHR(2), 0xf, 0xf, true));
  v = imax2(v, __builtin_amdgcn_update_dpp(0, v, DPP_ROW_SHR(4), 0xf, 0xf, true));
  v = imax2(v, __builtin_amdgcn_update_dpp(0, v, DPP_ROW_SHR(8), 0xf, 0xf, true));
  v = imax2(v, __builtin_amdgcn_update_dpp(0, v, DPP_ROW_BCAST15, 0xf, 0xf, true));
  v = imax2(v, __builtin_amdgcn_update_dpp(0, v, DPP_ROW_BCAST31, 0xf, 0xf, true));
  return __builtin_amdgcn_readlane(v, 63);
}

// wait lgkmcnt(0) only (vmcnt=63, exp=7): gfx9 encode 0xC07F = 49279
__device__ __forceinline__ void wait_lgkm0() {
  __builtin_amdgcn_sched_barrier(0);
  __builtin_amdgcn_s_waitcnt(49279);
  __builtin_amdgcn_sched_barrier(0);
}

// ========================= fast path =======================================

// Slim gather (R13/R18-proven): phoneme r-values + both Lpb arrays + out=0.
__global__ __launch_bounds__(256) void gather_ph_kernel(
    const float* __restrict__ ph_logits, const float* __restrict__ err_logits,
    const int* __restrict__ ph_tgt,
    float* __restrict__ Gph, float* __restrict__ Lpb_ph,
    float* __restrict__ Lpb_er, float* __restrict__ out) {
  const int bx = blockIdx.x, b = blockIdx.y;
  const int tid = threadIdx.x;
  const int lane = tid & 63, wv = tid >> 6;

  if (bx == 0 && b == 0 && tid == 0) *out = 0.f;  // chain kernel comes after

  // ---- error Lpb (wave 0, lanes 0..31) ----
  if (wv == 0 && lane < 32) {
    const int t = bx * 32 + lane;
    if (t < 2000) {
      const float4 v = *(const float4*)(err_logits + ((size_t)b * 2000 + t) * 4);
      const float z0 = v.x * LOG2E;
      const float s = fexp2(z0) + fexp2(v.y * LOG2E) + fexp2(v.z * LOG2E) +
                      fexp2(v.w * LOG2E);
      Lpb_er[(size_t)b * GROWS + t] = z0 - flog2(s);
    }
  }

  // ---- phoneme: 8 rows per wave ----
  const int* tb = ph_tgt + b * 200;
  int idx[4];
  float msk[4];
#pragma unroll
  for (int k = 0; k < 4; ++k) {
    const int si = lane * 4 + k;
    const int cls = (si < 200) ? tb[si] : 0;
    idx[k] = cls << 2;
    msk[k] = (si < 200) ? 1.0f : 0.0f;
  }
  const int t0 = (bx * 4 + wv) * 8;
  float z[8], e[8], s[8];
#pragma unroll
  for (int u = 0; u < 8; ++u) {
    const int t = t0 + u;
    const int tc = (t < 2000) ? t : 1999;
    z[u] = ph_logits[((size_t)b * 2000 + tc) * 64 + lane] * LOG2E;
    e[u] = fexp2(z[u]);
    s[u] = e[u];
  }
#pragma unroll
  for (int off = 32; off >= 1; off >>= 1) {
#pragma unroll
    for (int u = 0; u < 8; ++u) s[u] += __shfl_xor(s[u], off, 64);
  }
#pragma unroll
  for (int u = 0; u < 8; ++u) {
    const int t = t0 + u;
    if (t < 2000) {
      const float e0 = __int_as_float(
          __builtin_amdgcn_readlane(__float_as_int(e[u]), 0));
      const float inv0 = 1.0f / e0;
      float o[4];
#pragma unroll
      for (int k = 0; k < 4; ++k) {
        const float v = __int_as_float(
            __builtin_amdgcn_ds_bpermute(idx[k], __float_as_int(e[u])));
        o[k] = msk[k] * v * inv0;
      }
      *(float4*)(Gph + ((size_t)b * GROWS + t) * 256 + lane * 4) =
          make_float4(o[0], o[1], o[2], o[3]);
      if (lane == 0)  // lane 0's z is z0*log2e
        Lpb_ph[(size_t)b * GROWS + t] = z[u] - flog2(s[u]);
    }
  }
}

template <int P> struct RowP { float v[P]; };

__device__ __forceinline__ RowP<4> ld4(const float* p) {
  RowP<4> r;
  const float4 a = *(const float4*)p;
  r.v[0] = a.x; r.v[1] = a.y; r.v[2] = a.z; r.v[3] = a.w;
  return r;
}

// ---- scalar renorm/step for error path (P=1, R18-proven) ----
template <int P>
__device__ __forceinline__ void bl_renorm(double (&B)[P], double (&L)[P],
                                          int& K) {
  double mm = B[0];
#pragma unroll
  for (int k = 0; k < P; ++k) mm = fmax(fmax(mm, B[k]), L[k]);
  const int ex = (__double2hiint(mm) >> 20) & 0x7ff;
  const int emax = wave_imax(ex);
  if (emax > 0) {
    int d = 1523 - emax;            // pin band max to ~2^500
    if (d > 1023) d = 1023;
    if (d < -1022) d = -1022;
    const double sc = __hiloint2double((d + 1023) << 20, 0);
#pragma unroll
    for (int k = 0; k < P; ++k) { B[k] *= sc; L[k] *= sc; }
    K += d;
  }
}

template <int P>
__device__ __forceinline__ void bl_step(double (&B)[P], double (&L)[P],
                                        const double (&skipm)[P],
                                        const RowP<P>& f) {
  const double Lm1 = dpp_shr1_f64(L[P - 1]);
  double nB[P], nL[P];
#pragma unroll
  for (int k = 0; k < P; ++k) {
    const double Lp = (k >= 1) ? L[k - 1] : Lm1;
    nB[k] = B[k] + Lp;
    nL[k] = (double)f.v[k] * fma(skipm[k], Lp, B[k] + L[k]);
  }
#pragma unroll
  for (int k = 0; k < P; ++k) { B[k] = nB[k]; L[k] = nL[k]; }
}

// ---- packed-f64 renorm/step for phoneme path (P=4 as 2x double2) ----
__device__ __forceinline__ void bl_renorm_pk(v2d& B01, v2d& B23,
                                             v2d& L01, v2d& L23, int& K) {
  const double mm =
      fmax(fmax(fmax(B01[0], B01[1]), fmax(B23[0], B23[1])),
           fmax(fmax(L01[0], L01[1]), fmax(L23[0], L23[1])));
  const int ex = (__double2hiint(mm) >> 20) & 0x7ff;
  const int emax = wave_imax(ex);
  if (emax > 0) {
    int d = 1523 - emax;            // pin band max to ~2^500
    if (d > 1023) d = 1023;
    if (d < -1022) d = -1022;
    const double sc = __hiloint2double((d + 1023) << 20, 0);
    B01 *= sc; B23 *= sc; L01 *= sc; L23 *= sc;
    K += d;
  }
}

__device__ __forceinline__ void bl_step_pk(v2d& B01, v2d& B23,
                                           v2d& L01, v2d& L23,
                                           const v2d& sk01, const v2d& sk23,
                                           const RowP<4>& f) {
  const double Lm1 = dpp_shr1_f64(L23[1]);   // L[3] from prev lane
  v2d Lp01, Lp23;
  Lp01[0] = Lm1;     Lp01[1] = L01[0];
  Lp23[0] = L01[1];  Lp23[1] = L23[0];
  const v2d nB01 = B01 + Lp01;               // v_pk_add_f64
  const v2d nB23 = B23 + Lp23;
  v2d f01, f23;
  f01[0] = (double)f.v[0]; f01[1] = (double)f.v[1];
  f23[0] = (double)f.v[2]; f23[1] = (double)f.v[3];
  const v2d t01 = sk01 * Lp01 + (B01 + L01); // pk_add + pk_fma (contract)
  const v2d t23 = sk23 * Lp23 + (B23 + L23);
  L01 = f01 * t01;                           // v_pk_mul_f64
  L23 = f23 * t23;
  B01 = nB01;
  B23 = nB23;
}

// spb = sum_{t<len} Lpb[t], lane-parallel, x8 ILP
__device__ __forceinline__ float spb_sum(const float* __restrict__ Lpb,
                                         int len, int lane) {
  float spb = 0.f;
  for (int t0 = lane; t0 < len; t0 += 512) {
#pragma unroll
    for (int u = 0; u < 8; ++u) {
      const int t = t0 + u * 64;
      const int tc = (t < len) ? t : 0;        // always-valid address
      const float v = Lpb[tc];
      spb += (t < len) ? v : 0.0f;             // cndmask, no branch
    }
  }
#pragma unroll
  for (int off = 32; off >= 1; off >>= 1) spb += __shfl_xor(spb, off, 64);
  return spb;
}

// ---------------------------------------------------------------------------
// Chain kernel: 64 blocks x 64 thr.
//  blk [0,32):  error FULL chain (R18-proven inline-f, 8-row float4 groups).
//  blk [32,64): phoneme FULL chain (R9-literal loop, packed-f64 step).
// ---------------------------------------------------------------------------
__global__ __launch_bounds__(64) void ctc_chains2_kernel(
    const float* __restrict__ Gph, const float* __restrict__ err_logits,
    const int* __restrict__ ph_tgt, const int* __restrict__ err_tgt,
    const int* __restrict__ err_il, const int* __restrict__ ph_il,
    const int* __restrict__ err_tl, const int* __restrict__ ph_tl,
    const float* __restrict__ Lpb_ph, const float* __restrict__ Lpb_er,
    float* __restrict__ out) {
  __shared__ double sa[512];
  const int blk = blockIdx.x;
  const int lane = threadIdx.x;

  if (blk < 32) {
    // ================= error: full chain, P=1, inline f =================
    constexpr int S = 50;
    const int c = blk;
    const int* tb = err_tgt + c * 50;
    int len = err_il[c]; if (len > 2000) len = 2000;
    const int tl = err_tl[c];
    const float4* zr = (const float4*)(err_logits + (size_t)c * 2000 * 4);

    const float spb = spb_sum(Lpb_er + (size_t)c * GROWS, len, lane);
    const int c1 = tb[(lane < S) ? lane : (S - 1)];
    const float fmask = (lane < S) ? 1.0f : 0.0f;
    double skipm[1];
    skipm[0] = (lane >= 1 && lane < S && tb[lane] != tb[lane - 1]) ? 1.0 : 0.0;

    double B[1], L[1];
    B[0] = 0.0; L[0] = 0.0;
    {
      const float4 q0 = zr[0];
      const int c0 = tb[0];
      const float zc = (c0 == 1) ? q0.y : (c0 == 2) ? q0.z : q0.w;
      if (lane == 0) {
        B[0] = 1.0;
        L[0] = (double)fexp2((zc - q0.x) * LOG2E);
      }
    }
    int K = 0;

    const int nsteps = len - 1;          // rows 1..len-1
    const int ng = nsteps / 8;
    float4 bufA[8], bufB[8];
    if (ng >= 1) {
#pragma unroll
      for (int u = 0; u < 8; ++u) bufA[u] = zr[1 + u];
    }
    if (ng >= 2) {
#pragma unroll
      for (int u = 0; u < 8; ++u) bufB[u] = zr[9 + u];
    }
    int g = 0;
    for (; g + 2 <= ng; g += 2) {
      bl_renorm<1>(B, L, K);
      {
        const int gn = (g + 2 < ng) ? (g + 2) : 0;  // clamp re-reads rows 1..8
        const float4* nx = zr + 1 + gn * 8;
#pragma unroll
        for (int u = 0; u < 8; ++u) {
          RowP<1> f;
          const float4 q = bufA[u];
          const float zc = (c1 == 1) ? q.y : (c1 == 2) ? q.z : q.w;
          f.v[0] = fmask * fexp2((zc - q.x) * LOG2E);
          bl_step<1>(B, L, skipm, f);
          bufA[u] = nx[u];
        }
      }
      bl_renorm<1>(B, L, K);
      {
        const int gn = (g + 3 < ng) ? (g + 3) : 0;
        const float4* nx = zr + 1 + gn * 8;
#pragma unroll
        for (int u = 0; u < 8; ++u) {
          RowP<1> f;
          const float4 q = bufB[u];
          const float zc = (c1 == 1) ? q.y : (c1 == 2) ? q.z : q.w;
          f.v[0] = fmask * fexp2((zc - q.x) * LOG2E);
          bl_step<1>(B, L, skipm, f);
          bufB[u] = nx[u];
        }
      }
    }
    if (g < ng) {
      bl_renorm<1>(B, L, K);
#pragma unroll
      for (int u = 0; u < 8; ++u) {
        RowP<1> f;
        const float4 q = bufA[u];
        const float zc = (c1 == 1) ? q.y : (c1 == 2) ? q.z : q.w;
        f.v[0] = fmask * fexp2((zc - q.x) * LOG2E);
        bl_step<1>(B, L, skipm, f);
      }
      ++g;
    }
    {  // tail rows 1+ng*8 .. nsteps (<=7)
      const int tstart = 1 + ng * 8;
      float4 bufT[7];
#pragma unroll
      for (int u = 0; u < 7; ++u) {
        int t = tstart + u;
        if (t > nsteps) t = (nsteps > 0) ? nsteps : 1;
        bufT[u] = zr[t];
      }
#pragma unroll
      for (int u = 0; u < 7; ++u) {
        if (tstart + u <= nsteps) {
          if (u == 0) bl_renorm<1>(B, L, K);
          RowP<1> f;
          const float4 q = bufT[u];
          const float zc = (c1 == 1) ? q.y : (c1 == 2) ? q.z : q.w;
          f.v[0] = fmask * fexp2((zc - q.x) * LOG2E);
          bl_step<1>(B, L, skipm, f);
        }
      }
    }

    // readout: alpha[2tl-1] = L[tl-1], alpha[2tl] = B[tl]
    double* saB = sa;
    double* saL = sa + 64;
    saB[lane] = B[0];
    saL[lane] = L[0];
    wait_lgkm0();
    if (lane == 0) {
      const double a = saL[tl - 1] + saB[tl];
      float loss = (float)((double)K * LN2D - log(a) - (double)spb * LN2D);
      if (!(loss < 1e29f)) loss = 0.f;  // zero_infinity
      atomicAdd(out, loss / ((float)tl * 32.0f));
    }
    return;
  }

  // ============ phoneme: full chain, packed-f64, R9-literal loop ============
  constexpr int S = 200, LSTRIDE = 256;
  const int b = blk - 32;
  const int* tb = ph_tgt + b * 200;
  int len = ph_il[b]; if (len > 2000) len = 2000;
  const int tl = ph_tl[b];
  const float* Glab = Gph + (size_t)b * GROWS * 256;
  const float* gp = Glab + lane * 4;

  const float spb = spb_sum(Lpb_ph + (size_t)b * GROWS, len, lane);

  v2d sk01, sk23;
  {
    const int s0 = lane * 4;
    sk01[0] = (s0 >= 1 && s0 < S && tb[s0] != tb[s0 - 1]) ? 1.0 : 0.0;
    sk01[1] = (s0 + 1 < S && tb[s0 + 1] != tb[s0]) ? 1.0 : 0.0;
    sk23[0] = (s0 + 2 < S && tb[s0 + 2] != tb[s0 + 1]) ? 1.0 : 0.0;
    sk23[1] = (s0 + 3 < S && tb[s0 + 3] != tb[s0 + 2]) ? 1.0 : 0.0;
  }

  v2d B01 = {0.0, 0.0}, B23 = {0.0, 0.0};
  v2d L01 = {0.0, 0.0}, L23 = {0.0, 0.0};
  {
    const float r0 = Glab[0];  // lane0 slot0 = r_{tgt[0]}(0)
    if (lane == 0) { B01[0] = 1.0; L01[0] = (double)r0; }
  }
  int K = 0;

  const int ngroups = (len - 1) / 16;    // full groups: rows 1+16g..16+16g

  RowP<4> bufA[16], bufB[16];
  if (ngroups >= 1) {
    const float* rb = gp + (size_t)1 * LSTRIDE;
#pragma unroll
    for (int u = 0; u < 16; ++u) bufA[u] = ld4(rb + (size_t)u * LSTRIDE);
  }
  if (ngroups >= 2) {
    const float* rb = gp + (size_t)17 * LSTRIDE;
#pragma unroll
    for (int u = 0; u < 16; ++u) bufB[u] = ld4(rb + (size_t)u * LSTRIDE);
  }

  int g = 0;
  for (; g + 2 <= ngroups; g += 2) {
    // ---- group g from bufA; per-step refill with group g+2 (clamped) ----
    {
      bl_renorm_pk(B01, B23, L01, L23, K);
      const int gn = (g + 2 < ngroups) ? (g + 2) : 0;  // clamp: rows 1..16
      const float* nx = gp + (size_t)(1 + gn * 16) * LSTRIDE;
#pragma unroll
      for (int u = 0; u < 16; ++u) {
        bl_step_pk(B01, B23, L01, L23, sk01, sk23, bufA[u]);
        bufA[u] = ld4(nx + (size_t)u * LSTRIDE);
      }
    }
    // ---- group g+1 from bufB; per-step refill with group g+3 ----
    {
      bl_renorm_pk(B01, B23, L01, L23, K);
      const int gn = (g + 3 < ngroups) ? (g + 3) : 0;
      const float* nx = gp + (size_t)(1 + gn * 16) * LSTRIDE;
#pragma unroll
      for (int u = 0; u < 16; ++u) {
        bl_step_pk(B01, B23, L01, L23, sk01, sk23, bufB[u]);
        bufB[u] = ld4(nx + (size_t)u * LSTRIDE);
      }
    }
  }
  if (g < ngroups) {  // odd ngroups: last full group sits in bufA
    bl_renorm_pk(B01, B23, L01, L23, K);
#pragma unroll
    for (int u = 0; u < 16; ++u)
      bl_step_pk(B01, B23, L01, L23, sk01, sk23, bufA[u]);
    ++g;
  }

  // tail (<=15 rows): batch-prefetch, one latency hit total.
  {
    const int tstart = 1 + ngroups * 16;
    RowP<4> bufT[15];
#pragma unroll
    for (int u = 0; u < 15; ++u) {
      int t = tstart + u;
      if (t > len - 1) t = len - 1;            // always-valid address
      bufT[u] = ld4(gp + (size_t)t * LSTRIDE);
    }
#pragma unroll
    for (int u = 0; u < 15; ++u) {
      const int t = tstart + u;
      if (t < len) {
        if (u == 0) bl_renorm_pk(B01, B23, L01, L23, K);
        bl_step_pk(B01, B23, L01, L23, sk01, sk23, bufT[u]);
      }
    }
  }

  // readout: alpha[2tl-1] = L[tl-1], alpha[2tl] = B[tl]
  double* saB = sa;
  double* saL = sa + 256;
  saB[lane * 4 + 0] = B01[0]; saB[lane * 4 + 1] = B01[1];
  saB[lane * 4 + 2] = B23[0]; saB[lane * 4 + 3] = B23[1];
  saL[lane * 4 + 0] = L01[0]; saL[lane * 4 + 1] = L01[1];
  saL[lane * 4 + 2] = L23[0]; saL[lane * 4 + 3] = L23[1];
  wait_lgkm0();  // single-wave block: drain ds_writes, no barrier needed
  if (lane == 0) {
    const double a = saL[tl - 1] + saB[tl];
    float loss = (float)((double)K * LN2D - log(a) - (double)spb * LN2D);
    if (!(loss < 1e29f)) loss = 0.f;  // zero_infinity
    atomicAdd(out, loss / ((float)tl * 32.0f));
  }
}

// ========================= fallback path (R2, proven) ======================

__global__ __launch_bounds__(256) void softmax4_kernel(
    const float* __restrict__ x, float* __restrict__ p, int nrows) {
  int r = blockIdx.x * blockDim.x + threadIdx.x;
  if (r >= nrows) return;
  float4 v = *reinterpret_cast<const float4*>(x + (size_t)r * 4);
  float z0 = v.x * LOG2E, z1 = v.y * LOG2E, z2 = v.z * LOG2E, z3 = v.w * LOG2E;
  float m = fmaxf(fmaxf(z0, z1), fmaxf(z2, z3));
  float e0 = fexp2(z0 - m), e1 = fexp2(z1 - m);
  float e2 = fexp2(z2 - m), e3 = fexp2(z3 - m);
  float inv = 1.0f / (e0 + e1 + e2 + e3);
  float4 o;
  o.x = e0 * inv; o.y = e1 * inv; o.z = e2 * inv; o.w = e3 * inv;
  *reinterpret_cast<float4*>(p + (size_t)r * 4) = o;
}

__global__ __launch_bounds__(256) void softmax64_kernel(
    const float* __restrict__ x, float* __restrict__ p, int nrows) {
  int row = blockIdx.x * 4 + (threadIdx.x >> 6);
  int lane = threadIdx.x & 63;
  if (row >= nrows) return;
  float z = x[(size_t)row * 64 + lane] * LOG2E;
  float m = z;
#pragma unroll
  for (int off = 32; off >= 1; off >>= 1) m = fmaxf(m, __shfl_xor(m, off, 64));
  float e = fexp2(z - m);
  float s = e;
#pragma unroll
  for (int off = 32; off >= 1; off >>= 1) s += __shfl_xor(s, off, 64);
  p[(size_t)row * 64 + lane] = e * (1.0f / s);
}

template <int C, int S, int R>
__device__ __forceinline__ void ctc_chain_lin_fb(
    const float* __restrict__ p_b, const int* __restrict__ tgt_b,
    int len, int tl, float* __restrict__ out, double* sa) {
  constexpr int L = 2 * S + 1;
  const int lane = threadIdx.x;
  int idx[R];
  double skipm[R];
#pragma unroll
  for (int j = 0; j < R; ++j) {
    const int l = lane * R + j;
    int cls = 0;
    bool sk = false;
    if (l & 1) {
      const int s = (l - 1) >> 1;
      const int sc = (s < S) ? s : (S - 1);
      cls = tgt_b[sc];
      if (s >= 1 && s < S) sk = (cls != tgt_b[s - 1]);
    }
    idx[j] = cls * 4;
    skipm[j] = sk ? 1.0 : 0.0;
  }
  double alpha[R];
#pragma unroll
  for (int j = 0; j < R; ++j) {
    const int l = lane * R + j;
    alpha[j] = (l <= 1) ? (double)p_b[idx[j] >> 2] : 0.0;
  }
  int K = 0;
  const int cl = lane & (C - 1);
  float rv = p_b[(size_t)((1 < len - 1) ? 1 : (len - 1)) * C + cl];
  float pf[R];
#pragma unroll
  for (int j = 0; j < R; ++j)
    pf[j] = __int_as_float(__builtin_amdgcn_ds_bpermute(idx[j], __float_as_int(rv)));
  rv = p_b[(size_t)((2 < len - 1) ? 2 : (len - 1)) * C + cl];
  for (int t = 1; t < len; ++t) {
    if ((t & 31) == 0) {
      double m = alpha[0];
#pragma unroll
      for (int j = 1; j < R; ++j) m = fmax(m, alpha[j]);
#pragma unroll
      for (int off = 1; off < 64; off <<= 1) m = fmax(m, __shfl_xor(m, off, 64));
      const long long bits = __double_as_longlong(m);
      const int e = (int)((bits >> 52) & 0x7FF);
      if (e > 0) {
        const double sc = __longlong_as_double((long long)(2046 - e) << 52);
#pragma unroll
        for (int j = 0; j < R; ++j) alpha[j] *= sc;
        K += 1023 - e;
      }
    }
    const int tn = (t + 2 < len) ? (t + 2) : (len - 1);
    const float rvn = p_b[(size_t)tn * C + cl];
    float pfn[R];
#pragma unroll
    for (int j = 0; j < R; ++j)
      pfn[j] = __int_as_float(__builtin_amdgcn_ds_bpermute(idx[j], __float_as_int(rv)));
    double am1 = __shfl_up(alpha[R - 1], 1, 64);
    double am2 = __shfl_up(alpha[R - 2], 1, 64);
    if (lane == 0) { am1 = 0.0; am2 = 0.0; }
    double na[R];
#pragma unroll
    for (int j = 0; j < R; ++j) {
      const double a0 = alpha[j];
      const double a1 = (j >= 1) ? alpha[j - 1] : am1;
      const double a2 = (j >= 2) ? alpha[j - 2] : ((j == 1) ? am1 : am2);
      double s = a0 + a1;
      s = fma(skipm[j], a2, s);
      na[j] = (double)pf[j] * s;
    }
#pragma unroll
    for (int j = 0; j < R; ++j) alpha[j] = na[j];
#pragma unroll
    for (int j = 0; j < R; ++j) pf[j] = pfn[j];
    rv = rvn;
  }
#pragma unroll
  for (int j = 0; j < R; ++j) {
    const int l = lane * R + j;
    if (l < L) sa[l] = alpha[j];
  }
  __syncthreads();
  if (lane == 0) {
    const double a = sa[2 * tl - 1] + sa[2 * tl];
    float loss = (float)((double)K * LN2D - log(a));
    if (!(loss < 1e29f)) loss = 0.0f;
    atomicAdd(out, loss / ((float)tl * 32.0f));
  }
}

__global__ __launch_bounds__(64) void ctc_chains_fb_kernel(
    const float* __restrict__ p_err, const float* __restrict__ p_ph,
    const int* __restrict__ err_tgt, const int* __restrict__ ph_tgt,
    const int* __restrict__ err_il, const int* __restrict__ ph_il,
    const int* __restrict__ err_tl, const int* __restrict__ ph_tl,
    float* __restrict__ out) {
  __shared__ double sa[512];
  const int T = 2000;
  const int blk = blockIdx.x;
  if (blk < 32) {
    const int b = blk;
    int len = err_il[b]; if (len > T) len = T;
    ctc_chain_lin_fb<4, 50, 2>(p_err + (size_t)b * T * 4, err_tgt + b * 50, len,
                               err_tl[b], out, sa);
  } else {
    const int b = blk - 32;
    int len = ph_il[b]; if (len > T) len = T;
    ctc_chain_lin_fb<64, 200, 7>(p_ph + (size_t)b * T * 64, ph_tgt + b * 200,
                                 len, ph_tl[b], out, sa);
  }
}

// ========================= launch ==========================================

extern "C" void kernel_launch(void* const* d_in, const int* in_sizes, int n_in,
                              void* d_out, int out_size, void* d_ws,
                              size_t ws_size, hipStream_t stream) {
  const float* err_logits = (const float*)d_in[0];
  const float* ph_logits  = (const float*)d_in[1];
  const int* err_tgt = (const int*)d_in[2];
  const int* ph_tgt  = (const int*)d_in[3];
  const int* err_il  = (const int*)d_in[4];
  const int* ph_il   = (const int*)d_in[5];
  const int* err_tl  = (const int*)d_in[6];
  const int* ph_tl   = (const int*)d_in[7];
  float* out = (float*)d_out;

  const size_t gph = (size_t)32 * GROWS * 256;  // floats, 66.6 MB
  const size_t lpb = (size_t)32 * GROWS;        // floats, per task
  const size_t need = (gph + 2 * lpb) * sizeof(float);

  if (ws_size >= need) {
    float* Gph = (float*)d_ws;
    float* Lpb_ph = Gph + gph;
    float* Lpb_er = Lpb_ph + lpb;
    // gather zeroes *out (chain kernel is stream-ordered after it)
    gather_ph_kernel<<<dim3(63, 32), 256, 0, stream>>>(
        ph_logits, err_logits, ph_tgt, Gph, Lpb_ph, Lpb_er, out);
    ctc_chains2_kernel<<<64, 64, 0, stream>>>(
        Gph, err_logits, ph_tgt, err_tgt, err_il, ph_il, err_tl, ph_tl,
        Lpb_ph, Lpb_er, out);
  } else {
    (void)hipMemsetAsync(d_out, 0, sizeof(float), stream);
    const int B = 32, T = 2000;
    const int rows = B * T;
    float* p_err = (float*)d_ws;
    float* p_ph  = p_err + (size_t)rows * 4;
    softmax4_kernel<<<(rows + 255) / 256, 256, 0, stream>>>(err_logits, p_err, rows);
    softmax64_kernel<<<(rows + 3) / 4, 256, 0, stream>>>(ph_logits, p_ph, rows);
    ctc_chains_fb_kernel<<<64, 64, 0, stream>>>(p_err, p_ph, err_tgt, ph_tgt,
                                                err_il, ph_il, err_tl, ph_tl, out);
  }
}